// Round 4
// baseline (376.360 us; speedup 1.0000x reference)
//
#include <hip/hip_runtime.h>
#include <hip/hip_bf16.h>
#include <cmath>
#include <complex>

// ---------------- static problem config ----------------
#define NDIM1 576
#define NDIM2 9
#define NDIMO 576

typedef __attribute__((ext_vector_type(8))) short short8;
typedef __attribute__((ext_vector_type(4))) float f32x4;

struct CGTab { float v[363]; };

union U8 { unsigned short s[8]; short8 v; };

__device__ inline unsigned short f2bf(float x) {
  return __builtin_bit_cast(unsigned short, __float2bfloat16(x));
}

// real-basis CG selection rule (superset of nonzeros):
constexpr bool cg_nonzero(int m1, int m2, int m3) {
  int a1 = m1 < 0 ? -m1 : m1, a2 = m2 < 0 ? -m2 : m2, a3 = m3 < 0 ? -m3 : m3;
  int d = a1 > a2 ? a1 - a2 : a2 - a1;
  bool mag = (a3 == a1 + a2) || (a3 == d);
  int neg = (m1 < 0) + (m2 < 0) + (m3 < 0);
  return mag && ((neg & 1) == 0);
}

// ---------------- prep kernel: pack W into bf16 MFMA B-fragments ----------------
// layout: wf[((p*2+s)*4+v)*64 + lane] = short8 of 8 bf16
__global__ __launch_bounds__(256) void prep_w_kernel(const float* __restrict__ W,
                                                     short8* __restrict__ wf) {
  int idx = blockIdx.x * 256 + threadIdx.x;
  if (idx >= 11 * 2 * 4 * 64) return;
  int lane = idx & 63;
  int v = (idx >> 6) & 3;
  int s = (idx >> 8) & 1;
  int p = idx >> 9;
  int g = lane >> 4, r16 = lane & 15;
  const float* wp = W + p * 4096 + (s * 32 + g * 8) * 64 + v * 16 + r16;
  U8 u;
#pragma unroll
  for (int t = 0; t < 8; t++) u.s[t] = f2bf(wp[t * 64]);
  wf[idx] = u.v;
}

// ---------------- device helpers ----------------
template <int NI>
__device__ inline void issue_x1(const float* __restrict__ row, int g, f32x4 (&raw)[4 * NI]) {
#pragma unroll
  for (int s = 0; s < 2; s++) {
    const f32x4* src = (const f32x4*)(row + (s * 32 + g * 8) * NI);
#pragma unroll
    for (int q = 0; q < 2 * NI; q++) raw[s * 2 * NI + q] = src[q];
  }
}

template <int NI>
__device__ inline void convert_x1(const f32x4 (&raw)[4 * NI], short8 (&af)[NI][2]) {
#pragma unroll
  for (int s = 0; s < 2; s++) {
#pragma unroll
    for (int i = 0; i < NI; i++) {
      U8 u;
#pragma unroll
      for (int t = 0; t < 8; t++) {
        int idx = t * NI + i;
        u.s[t] = f2bf(raw[s * 2 * NI + (idx >> 2)][idx & 3]);
      }
      af[i][s] = u.v;
    }
  }
}

template <int NI>
__device__ inline void run_path(const short8* __restrict__ wf, int p, int v, int lane,
                                const short8 (&af)[NI][2], f32x4 (&acc)[NI]) {
#pragma unroll
  for (int i = 0; i < NI; i++) acc[i] = (f32x4){0.f, 0.f, 0.f, 0.f};
#pragma unroll
  for (int s = 0; s < 2; s++) {
    short8 b = wf[((p * 2 + s) * 4 + v) * 64 + lane];
#pragma unroll
    for (int i = 0; i < NI; i++)
      acc[i] = __builtin_amdgcn_mfma_f32_16x16x32_bf16(af[i][s], b, acc[i], 0, 0, 0);
  }
}

template <int L1, int L2, int LO, int CGO, int NI>
__device__ inline void epilogue(const float* __restrict__ cg, const f32x4 (&acc)[NI],
                                const float (&x2v)[4][9], float (&outr)[4][9]) {
  constexpr int JO = (L2 == 0) ? 0 : (L2 == 1 ? 1 : 4);
  constexpr int KO = (LO == 0) ? 0 : (LO == 1 ? 1 : 4);
#pragma unroll
  for (int i = 0; i < 2 * L1 + 1; i++) {
#pragma unroll
    for (int j = 0; j < 2 * L2 + 1; j++) {
#pragma unroll
      for (int k = 0; k < 2 * LO + 1; k++) {
        if (!cg_nonzero(i - L1, j - L2, k - LO)) continue;  // folds after unroll
        float c = cg[CGO + (i * (2 * L2 + 1) + j) * (2 * LO + 1) + k];
#pragma unroll
        for (int r = 0; r < 4; r++)
          outr[r][KO + k] = fmaf(c * x2v[r][JO + j], acc[i][r], outr[r][KO + k]);
      }
    }
  }
}

// ---------------- main kernel ----------------
// Block = 64 n-rows, 4 waves; wave wv owns rows [n0+16*wv, +16) and loops
// over all 4 w-tiles (v). x1 loaded once per wave (no cross-wave redundancy),
// converted once into persistent bf16 A-frags, reused for all 4 v.
__global__ __launch_bounds__(256, 2) void TPWithWeights_44925357916441_kernel(
    const float* __restrict__ x1, const float* __restrict__ x2,
    const short8* __restrict__ wf, float* __restrict__ out, CGTab tab) {
  const int lane = threadIdx.x & 63;
  const int wv = threadIdx.x >> 6;      // wave id -> n-row sub-tile
  const int n0 = blockIdx.x << 6;       // 64 rows per block
  const int nb = n0 + wv * 16;          // this wave's 16-row tile
  const int g = lane >> 4, r16 = lane & 15;
  const float* cg = tab.v;
  const float* rowbase = x1 + (size_t)(nb + r16) * NDIM1;

  // ---- load + convert phase ----
  f32x4 raw0[4], raw1[12], xv[9];
  issue_x1<1>(rowbase + 0, g, raw0);
  issue_x1<3>(rowbase + 64, g, raw1);
  {
    const f32x4* p2 = (const f32x4*)(x2 + (size_t)(nb + g * 4) * NDIM2);
#pragma unroll
    for (int q = 0; q < 9; q++) xv[q] = p2[q];
  }

  short8 af0[1][2];
  convert_x1<1>(raw0, af0);

  f32x4 raw2[20];
  issue_x1<5>(rowbase + 256, g, raw2);

  short8 af1[3][2];
  convert_x1<3>(raw1, af1);
  short8 af2[5][2];
  convert_x1<5>(raw2, af2);

  float x2v[4][9];
#pragma unroll
  for (int r = 0; r < 4; r++)
#pragma unroll
    for (int j = 0; j < 9; j++) {
      int idx = r * 9 + j;
      x2v[r][j] = xv[idx >> 2][idx & 3];
    }

  // ---- per-w-tile loop: all 11 paths, then store ----
  for (int v = 0; v < 4; v++) {
    float outr[4][9];
#pragma unroll
    for (int r = 0; r < 4; r++)
#pragma unroll
      for (int j = 0; j < 9; j++) outr[r][j] = 0.f;

    {  // chunk i1=0 (l1=0), paths 0..2
      f32x4 acc[1];
      run_path<1>(wf, 0, v, lane, af0, acc); epilogue<0, 0, 0, 0, 1>(cg, acc, x2v, outr);
      run_path<1>(wf, 1, v, lane, af0, acc); epilogue<0, 1, 1, 1, 1>(cg, acc, x2v, outr);
      run_path<1>(wf, 2, v, lane, af0, acc); epilogue<0, 2, 2, 10, 1>(cg, acc, x2v, outr);
    }
    {  // chunk i1=1 (l1=1), paths 3..6
      f32x4 acc[3];
      run_path<3>(wf, 3, v, lane, af1, acc); epilogue<1, 0, 1, 35, 3>(cg, acc, x2v, outr);
      run_path<3>(wf, 4, v, lane, af1, acc); epilogue<1, 1, 0, 44, 3>(cg, acc, x2v, outr);
      run_path<3>(wf, 5, v, lane, af1, acc); epilogue<1, 1, 2, 53, 3>(cg, acc, x2v, outr);
      run_path<3>(wf, 6, v, lane, af1, acc); epilogue<1, 2, 1, 98, 3>(cg, acc, x2v, outr);
    }
    {  // chunk i1=2 (l1=2), paths 7..10
      f32x4 acc[5];
      run_path<5>(wf, 7, v, lane, af2, acc); epilogue<2, 0, 2, 143, 5>(cg, acc, x2v, outr);
      run_path<5>(wf, 8, v, lane, af2, acc); epilogue<2, 1, 1, 168, 5>(cg, acc, x2v, outr);
      run_path<5>(wf, 9, v, lane, af2, acc); epilogue<2, 2, 0, 213, 5>(cg, acc, x2v, outr);
      run_path<5>(wf, 10, v, lane, af2, acc); epilogue<2, 2, 2, 238, 5>(cg, acc, x2v, outr);
    }

    const int w = v * 16 + r16;
#pragma unroll
    for (int r = 0; r < 4; r++) {
      float* op = out + (size_t)(nb + g * 4 + r) * NDIMO;
      op[w] = outr[r][0];
#pragma unroll
      for (int k = 0; k < 3; k++) op[64 + w * 3 + k] = outr[r][1 + k];
#pragma unroll
      for (int k = 0; k < 5; k++) op[256 + w * 5 + k] = outr[r][4 + k];
    }
  }
}

// ---------------- host: exact port of reference CG computation ----------------
static double h_fact(int n) { double r = 1.0; for (int i = 2; i <= n; i++) r *= (double)i; return r; }
static inline int imax3(int a, int b, int c) { int m = a > b ? a : b; return m > c ? m : c; }
static inline int imin3(int a, int b, int c) { int m = a < b ? a : b; return m < c ? m : c; }

static double su2_cg(int j1, int m1, int j2, int m2, int j3, int m3) {
  if (m3 != m1 + m2) return 0.0;
  int vmin = imax3(-j1 + j2 + m3, -j1 + m1, 0);
  int vmax = imin3(j2 + j3 + m1, j3 - j1 + j2, j3 + m3);
  double C = sqrt((2.0 * j3 + 1.0) * h_fact(j3 + j1 - j2) * h_fact(j3 - j1 + j2) *
                  h_fact(j1 + j2 - j3) * h_fact(j3 + m3) * h_fact(j3 - m3) /
                  (h_fact(j1 + j2 + j3 + 1) * h_fact(j1 - m1) * h_fact(j1 + m1) *
                   h_fact(j2 - m2) * h_fact(j2 + m2)));
  double S = 0.0;
  for (int vv = vmin; vv <= vmax; vv++) {
    double sg = ((vv + j2 + m2) & 1) ? -1.0 : 1.0;
    S += sg * h_fact(j2 + j3 + m1 - vv) * h_fact(j1 - m1 + vv) /
         (h_fact(vv) * h_fact(j3 - j1 + j2 - vv) * h_fact(j3 + m3 - vv) * h_fact(vv + j1 - j2 - m3));
  }
  return C * S;
}

static void cb_r2c(int l, std::complex<double> q[5][5]) {
  for (int a = 0; a < 5; a++) for (int b = 0; b < 5; b++) q[a][b] = 0.0;
  const double is2 = 1.0 / sqrt(2.0);
  for (int m = -l; m < 0; m++) {
    q[l + m][l - m] = is2;
    q[l + m][l + m] = std::complex<double>(0.0, -is2);
  }
  q[l][l] = 1.0;
  for (int m = 1; m <= l; m++) {
    double sg = (m & 1) ? -1.0 : 1.0;
    q[l + m][l + m] = sg * is2;
    q[l + m][l - m] = std::complex<double>(0.0, sg * is2);
  }
  std::complex<double> f(1.0, 0.0);
  for (int t = 0; t < l; t++) f *= std::complex<double>(0.0, -1.0);
  for (int a = 0; a < 2 * l + 1; a++) for (int b = 0; b < 2 * l + 1; b++) q[a][b] *= f;
}

static void cg_real(int l1, int l2, int l3, double outm[5][5][5]) {
  std::complex<double> q1[5][5], q2[5][5], q3[5][5];
  cb_r2c(l1, q1); cb_r2c(l2, q2); cb_r2c(l3, q3);
  double nrm = 0.0;
  for (int x = 0; x < 2 * l1 + 1; x++)
    for (int y = 0; y < 2 * l2 + 1; y++)
      for (int z = 0; z < 2 * l3 + 1; z++) {
        std::complex<double> a(0.0, 0.0);
        for (int i = 0; i < 2 * l1 + 1; i++)
          for (int k = 0; k < 2 * l2 + 1; k++)
            for (int n = 0; n < 2 * l3 + 1; n++) {
              double s = su2_cg(l1, i - l1, l2, k - l2, l3, n - l3);
              if (s != 0.0) a += q1[i][x] * q2[k][y] * std::conj(q3[n][z]) * s;
            }
        outm[x][y][z] = a.real();
        nrm += a.real() * a.real();
      }
  nrm = sqrt(nrm);
  for (int x = 0; x < 2 * l1 + 1; x++)
    for (int y = 0; y < 2 * l2 + 1; y++)
      for (int z = 0; z < 2 * l3 + 1; z++) outm[x][y][z] /= nrm;
}

static void build_cg_tables(CGTab& tab) {
  const int PL1[11] = {0, 0, 0, 1, 1, 1, 1, 2, 2, 2, 2};
  const int PL2[11] = {0, 1, 2, 0, 1, 1, 2, 0, 1, 2, 2};
  const int PLO[11] = {0, 1, 2, 1, 0, 2, 1, 2, 1, 0, 2};
  const int CGO[11] = {0, 1, 10, 35, 44, 53, 98, 143, 168, 213, 238};
  const double pw_io[3] = {sqrt(1.0 / 192.0), sqrt(3.0 / 256.0), sqrt(5.0 / 256.0)};
  for (int p = 0; p < 11; p++) {
    int l1 = PL1[p], l2 = PL2[p], lo = PLO[p];
    double c[5][5][5];
    cg_real(l1, l2, lo, c);
    double pw = pw_io[lo];
    for (int i = 0; i < 2 * l1 + 1; i++)
      for (int j = 0; j < 2 * l2 + 1; j++)
        for (int k = 0; k < 2 * lo + 1; k++)
          tab.v[CGO[p] + (i * (2 * l2 + 1) + j) * (2 * lo + 1) + k] = (float)(pw * c[i][j][k]);
  }
}

// ---------------- launch ----------------
extern "C" void kernel_launch(void* const* d_in, const int* in_sizes, int n_in,
                              void* d_out, int out_size, void* d_ws, size_t ws_size,
                              hipStream_t stream) {
  const float* x1 = (const float*)d_in[0];
  const float* x2 = (const float*)d_in[1];
  const float* W  = (const float*)d_in[2];
  float* out = (float*)d_out;

  int N = in_sizes[0] / NDIM1;  // 32768

  CGTab tab;
  build_cg_tables(tab);  // deterministic host-side computation, ~µs

  short8* wf = (short8*)d_ws;  // 11*2*4*64 * 16B = 90112 B

  hipLaunchKernelGGL(prep_w_kernel, dim3(22), dim3(256), 0, stream, W, wf);
  hipLaunchKernelGGL(TPWithWeights_44925357916441_kernel, dim3(N / 64), dim3(256), 0, stream,
                     x1, x2, wf, out, tab);
}

// Round 5
// 50.199 us; speedup vs baseline: 7.4974x; 7.4974x over previous
//
#include <hip/hip_runtime.h>
#include <hip/hip_bf16.h>
#include <cmath>
#include <complex>

// ---------------- static problem config ----------------
#define NDIM1 576
#define NDIM2 9
#define NDIMO 576
#define ROWB 2304            // bytes per x1 row (576 f32)
#define TILEB 36864          // 16 rows * 2304 B

typedef __attribute__((ext_vector_type(8))) short short8;
typedef __attribute__((ext_vector_type(4))) float f32x4;

struct CGTab { float v[363]; };

union U8 { unsigned short s[8]; short8 v; };

__device__ inline unsigned short f2bf(float x) {
  return __builtin_bit_cast(unsigned short, __float2bfloat16(x));
}

// real-basis CG selection rule (superset of nonzeros):
constexpr bool cg_nonzero(int m1, int m2, int m3) {
  int a1 = m1 < 0 ? -m1 : m1, a2 = m2 < 0 ? -m2 : m2, a3 = m3 < 0 ? -m3 : m3;
  int d = a1 > a2 ? a1 - a2 : a2 - a1;
  bool mag = (a3 == a1 + a2) || (a3 == d);
  int neg = (m1 < 0) + (m2 < 0) + (m3 < 0);
  return mag && ((neg & 1) == 0);
}

// ---------------- prep kernel: pack W into bf16 MFMA B-fragments ----------------
__global__ __launch_bounds__(256) void prep_w_kernel(const float* __restrict__ W,
                                                     short8* __restrict__ wf) {
  int idx = blockIdx.x * 256 + threadIdx.x;
  if (idx >= 11 * 2 * 4 * 64) return;
  int lane = idx & 63;
  int v = (idx >> 6) & 3;
  int s = (idx >> 8) & 1;
  int p = idx >> 9;
  int g = lane >> 4, r16 = lane & 15;
  const float* wp = W + p * 4096 + (s * 32 + g * 8) * 64 + v * 16 + r16;
  U8 u;
#pragma unroll
  for (int t = 0; t < 8; t++) u.s[t] = f2bf(wp[t * 64]);
  wf[idx] = u.v;
}

// ---------------- device helpers ----------------
typedef __attribute__((address_space(1))) const unsigned int gu32;
typedef __attribute__((address_space(3))) unsigned int lu32;

// read one i1-chunk's raw f32 data from swizzled LDS tile
template <int NI, int OFFB>  // OFFB = chunk float offset * 4 (bytes)
__device__ inline void load_lds_chunk(const char* tilebase, int g, int r16,
                                      f32x4 (&raw)[4 * NI]) {
  const char* rowp = tilebase + r16 * ROWB;
  const int rowx = (r16 & 7) << 4;
#pragma unroll
  for (int s = 0; s < 2; s++) {
#pragma unroll
    for (int q = 0; q < 2 * NI; q++) {
      int cb = OFFB + ((s * 32 + g * 8) * NI) * 4 + q * 16;
      raw[s * 2 * NI + q] = *(const f32x4*)(rowp + (cb ^ rowx));
    }
  }
}

template <int NI>
__device__ inline void convert_x1(const f32x4 (&raw)[4 * NI], short8 (&af)[NI][2]) {
#pragma unroll
  for (int s = 0; s < 2; s++) {
#pragma unroll
    for (int i = 0; i < NI; i++) {
      U8 u;
#pragma unroll
      for (int t = 0; t < 8; t++) {
        int idx = t * NI + i;
        u.s[t] = f2bf(raw[s * 2 * NI + (idx >> 2)][idx & 3]);
      }
      af[i][s] = u.v;
    }
  }
}

template <int NI>
__device__ inline void run_path(const short8* __restrict__ wf, int p, int v, int lane,
                                const short8 (&af)[NI][2], f32x4 (&acc)[NI]) {
#pragma unroll
  for (int i = 0; i < NI; i++) acc[i] = (f32x4){0.f, 0.f, 0.f, 0.f};
#pragma unroll
  for (int s = 0; s < 2; s++) {
    short8 b = wf[((p * 2 + s) * 4 + v) * 64 + lane];
#pragma unroll
    for (int i = 0; i < NI; i++)
      acc[i] = __builtin_amdgcn_mfma_f32_16x16x32_bf16(af[i][s], b, acc[i], 0, 0, 0);
  }
}

template <int L1, int L2, int LO, int CGO, int NI>
__device__ inline void epilogue(const float* __restrict__ cg, const f32x4 (&acc)[NI],
                                const float (&x2v)[4][9], float (&outr)[4][9]) {
  constexpr int JO = (L2 == 0) ? 0 : (L2 == 1 ? 1 : 4);
  constexpr int KO = (LO == 0) ? 0 : (LO == 1 ? 1 : 4);
#pragma unroll
  for (int i = 0; i < 2 * L1 + 1; i++) {
#pragma unroll
    for (int j = 0; j < 2 * L2 + 1; j++) {
#pragma unroll
      for (int k = 0; k < 2 * LO + 1; k++) {
        if (!cg_nonzero(i - L1, j - L2, k - LO)) continue;  // folds after unroll
        float c = cg[CGO + (i * (2 * L2 + 1) + j) * (2 * LO + 1) + k];
#pragma unroll
        for (int r = 0; r < 4; r++)
          outr[r][KO + k] = fmaf(c * x2v[r][JO + j], acc[i][r], outr[r][KO + k]);
      }
    }
  }
}

// ---------------- main kernel ----------------
// Block = 16 n-rows, 4 waves; wave v owns w-tile [16v,16v+16).
// x1 tile staged to LDS via global_load_lds (16B wide, XOR-swizzled via
// pre-swizzled SOURCE address; LDS dest linear), read back swizzled.
__global__ __launch_bounds__(256) void TPWithWeights_44925357916441_kernel(
    const float* __restrict__ x1, const float* __restrict__ x2,
    const short8* __restrict__ wf, float* __restrict__ out, CGTab tab) {
  __shared__ float tile[TILEB / 4];

  const int lane = threadIdx.x & 63;
  const int v = threadIdx.x >> 6;   // wave id -> w sub-tile
  const int n0 = blockIdx.x << 4;   // 16 n-rows per block
  const int g = lane >> 4, r16 = lane & 15;
  const float* cg = tab.v;

  // ---- stage x1 tile: 36 chunks of 1 KB, 9 per wave, all in flight ----
  const char* x1base = (const char*)(x1 + (size_t)n0 * NDIM1);
#pragma unroll
  for (int ch = 0; ch < 9; ch++) {
    const int c = v * 9 + ch;
    const int P = c * 1024 + lane * 16;       // physical LDS byte this lane fills
    const int row = P / ROWB;                 // logical row
    const int rem = P - row * ROWB;           // logical col-byte (linear)
    const int sb = rem ^ ((row & 7) << 4);    // inverse-swizzle source (XOR involution)
    const char* src = x1base + row * ROWB + sb;
    __builtin_amdgcn_global_load_lds((gu32*)src, (lu32*)(tile + c * 256), 16, 0, 0);
  }

  // ---- x2 for this lane's 4 rows (regular global loads, fly with staging) ----
  f32x4 xv[9];
  {
    const f32x4* p2 = (const f32x4*)(x2 + (size_t)(n0 + g * 4) * NDIM2);
#pragma unroll
    for (int q = 0; q < 9; q++) xv[q] = p2[q];
  }

  float x2v[4][9];
  float outr[4][9];
#pragma unroll
  for (int r = 0; r < 4; r++)
#pragma unroll
    for (int j = 0; j < 9; j++) {
      int idx = r * 9 + j;
      x2v[r][j] = xv[idx >> 2][idx & 3];
      outr[r][j] = 0.f;
    }

  __syncthreads();  // drains vmcnt (staging complete) + barrier

  const char* tb = (const char*)tile;

  {  // chunk i1=0 (l1=0), paths 0..2
    f32x4 raw[4]; short8 af[1][2]; f32x4 acc[1];
    load_lds_chunk<1, 0>(tb, g, r16, raw);
    convert_x1<1>(raw, af);
    run_path<1>(wf, 0, v, lane, af, acc); epilogue<0, 0, 0, 0, 1>(cg, acc, x2v, outr);
    run_path<1>(wf, 1, v, lane, af, acc); epilogue<0, 1, 1, 1, 1>(cg, acc, x2v, outr);
    run_path<1>(wf, 2, v, lane, af, acc); epilogue<0, 2, 2, 10, 1>(cg, acc, x2v, outr);
  }
  {  // chunk i1=1 (l1=1), paths 3..6
    f32x4 raw[12]; short8 af[3][2]; f32x4 acc[3];
    load_lds_chunk<3, 256>(tb, g, r16, raw);
    convert_x1<3>(raw, af);
    run_path<3>(wf, 3, v, lane, af, acc); epilogue<1, 0, 1, 35, 3>(cg, acc, x2v, outr);
    run_path<3>(wf, 4, v, lane, af, acc); epilogue<1, 1, 0, 44, 3>(cg, acc, x2v, outr);
    run_path<3>(wf, 5, v, lane, af, acc); epilogue<1, 1, 2, 53, 3>(cg, acc, x2v, outr);
    run_path<3>(wf, 6, v, lane, af, acc); epilogue<1, 2, 1, 98, 3>(cg, acc, x2v, outr);
  }
  {  // chunk i1=2 (l1=2), paths 7..10
    f32x4 raw[20]; short8 af[5][2]; f32x4 acc[5];
    load_lds_chunk<5, 1024>(tb, g, r16, raw);
    convert_x1<5>(raw, af);
    run_path<5>(wf, 7, v, lane, af, acc); epilogue<2, 0, 2, 143, 5>(cg, acc, x2v, outr);
    run_path<5>(wf, 8, v, lane, af, acc); epilogue<2, 1, 1, 168, 5>(cg, acc, x2v, outr);
    run_path<5>(wf, 9, v, lane, af, acc); epilogue<2, 2, 0, 213, 5>(cg, acc, x2v, outr);
    run_path<5>(wf, 10, v, lane, af, acc); epilogue<2, 2, 2, 238, 5>(cg, acc, x2v, outr);
  }

  const int w = v * 16 + r16;
#pragma unroll
  for (int r = 0; r < 4; r++) {
    float* op = out + (size_t)(n0 + g * 4 + r) * NDIMO;
    op[w] = outr[r][0];
#pragma unroll
    for (int k = 0; k < 3; k++) op[64 + w * 3 + k] = outr[r][1 + k];
#pragma unroll
    for (int k = 0; k < 5; k++) op[256 + w * 5 + k] = outr[r][4 + k];
  }
}

// ---------------- host: exact port of reference CG computation ----------------
static double h_fact(int n) { double r = 1.0; for (int i = 2; i <= n; i++) r *= (double)i; return r; }
static inline int imax3(int a, int b, int c) { int m = a > b ? a : b; return m > c ? m : c; }
static inline int imin3(int a, int b, int c) { int m = a < b ? a : b; return m < c ? m : c; }

static double su2_cg(int j1, int m1, int j2, int m2, int j3, int m3) {
  if (m3 != m1 + m2) return 0.0;
  int vmin = imax3(-j1 + j2 + m3, -j1 + m1, 0);
  int vmax = imin3(j2 + j3 + m1, j3 - j1 + j2, j3 + m3);
  double C = sqrt((2.0 * j3 + 1.0) * h_fact(j3 + j1 - j2) * h_fact(j3 - j1 + j2) *
                  h_fact(j1 + j2 - j3) * h_fact(j3 + m3) * h_fact(j3 - m3) /
                  (h_fact(j1 + j2 + j3 + 1) * h_fact(j1 - m1) * h_fact(j1 + m1) *
                   h_fact(j2 - m2) * h_fact(j2 + m2)));
  double S = 0.0;
  for (int vv = vmin; vv <= vmax; vv++) {
    double sg = ((vv + j2 + m2) & 1) ? -1.0 : 1.0;
    S += sg * h_fact(j2 + j3 + m1 - vv) * h_fact(j1 - m1 + vv) /
         (h_fact(vv) * h_fact(j3 - j1 + j2 - vv) * h_fact(j3 + m3 - vv) * h_fact(vv + j1 - j2 - m3));
  }
  return C * S;
}

static void cb_r2c(int l, std::complex<double> q[5][5]) {
  for (int a = 0; a < 5; a++) for (int b = 0; b < 5; b++) q[a][b] = 0.0;
  const double is2 = 1.0 / sqrt(2.0);
  for (int m = -l; m < 0; m++) {
    q[l + m][l - m] = is2;
    q[l + m][l + m] = std::complex<double>(0.0, -is2);
  }
  q[l][l] = 1.0;
  for (int m = 1; m <= l; m++) {
    double sg = (m & 1) ? -1.0 : 1.0;
    q[l + m][l + m] = sg * is2;
    q[l + m][l - m] = std::complex<double>(0.0, sg * is2);
  }
  std::complex<double> f(1.0, 0.0);
  for (int t = 0; t < l; t++) f *= std::complex<double>(0.0, -1.0);
  for (int a = 0; a < 2 * l + 1; a++) for (int b = 0; b < 2 * l + 1; b++) q[a][b] *= f;
}

static void cg_real(int l1, int l2, int l3, double outm[5][5][5]) {
  std::complex<double> q1[5][5], q2[5][5], q3[5][5];
  cb_r2c(l1, q1); cb_r2c(l2, q2); cb_r2c(l3, q3);
  double nrm = 0.0;
  for (int x = 0; x < 2 * l1 + 1; x++)
    for (int y = 0; y < 2 * l2 + 1; y++)
      for (int z = 0; z < 2 * l3 + 1; z++) {
        std::complex<double> a(0.0, 0.0);
        for (int i = 0; i < 2 * l1 + 1; i++)
          for (int k = 0; k < 2 * l2 + 1; k++)
            for (int n = 0; n < 2 * l3 + 1; n++) {
              double s = su2_cg(l1, i - l1, l2, k - l2, l3, n - l3);
              if (s != 0.0) a += q1[i][x] * q2[k][y] * std::conj(q3[n][z]) * s;
            }
        outm[x][y][z] = a.real();
        nrm += a.real() * a.real();
      }
  nrm = sqrt(nrm);
  for (int x = 0; x < 2 * l1 + 1; x++)
    for (int y = 0; y < 2 * l2 + 1; y++)
      for (int z = 0; z < 2 * l3 + 1; z++) outm[x][y][z] /= nrm;
}

static void build_cg_tables(CGTab& tab) {
  const int PL1[11] = {0, 0, 0, 1, 1, 1, 1, 2, 2, 2, 2};
  const int PL2[11] = {0, 1, 2, 0, 1, 1, 2, 0, 1, 2, 2};
  const int PLO[11] = {0, 1, 2, 1, 0, 2, 1, 2, 1, 0, 2};
  const int CGO[11] = {0, 1, 10, 35, 44, 53, 98, 143, 168, 213, 238};
  const double pw_io[3] = {sqrt(1.0 / 192.0), sqrt(3.0 / 256.0), sqrt(5.0 / 256.0)};
  for (int p = 0; p < 11; p++) {
    int l1 = PL1[p], l2 = PL2[p], lo = PLO[p];
    double c[5][5][5];
    cg_real(l1, l2, lo, c);
    double pw = pw_io[lo];
    for (int i = 0; i < 2 * l1 + 1; i++)
      for (int j = 0; j < 2 * l2 + 1; j++)
        for (int k = 0; k < 2 * lo + 1; k++)
          tab.v[CGO[p] + (i * (2 * l2 + 1) + j) * (2 * lo + 1) + k] = (float)(pw * c[i][j][k]);
  }
}

// ---------------- launch ----------------
extern "C" void kernel_launch(void* const* d_in, const int* in_sizes, int n_in,
                              void* d_out, int out_size, void* d_ws, size_t ws_size,
                              hipStream_t stream) {
  const float* x1 = (const float*)d_in[0];
  const float* x2 = (const float*)d_in[1];
  const float* W  = (const float*)d_in[2];
  float* out = (float*)d_out;

  int N = in_sizes[0] / NDIM1;  // 32768

  CGTab tab;
  build_cg_tables(tab);  // deterministic host-side computation, ~µs

  short8* wf = (short8*)d_ws;  // 11*2*4*64 * 16B = 90112 B

  hipLaunchKernelGGL(prep_w_kernel, dim3(22), dim3(256), 0, stream, W, wf);
  hipLaunchKernelGGL(TPWithWeights_44925357916441_kernel, dim3(N / 16), dim3(256), 0, stream,
                     x1, x2, wf, out, tab);
}